// Round 3
// baseline (154.334 us; speedup 1.0000x reference)
//
#include <hip/hip_runtime.h>

#define NS 8192
#define EMBED 128
#define ROWCHUNK 512             // grid.y = 16 chunks of 512 rows
#define NPANEL (ROWCHUNK / 32)   // 16 panels of 32 rows
#define AROW 12                  // correction-hist row stride (11 bins + 1 pad)
#define INV64K (1.0f / 65536.0f)

typedef __bf16 bf16x8 __attribute__((ext_vector_type(8)));
typedef float f32x4 __attribute__((ext_vector_type(4)));
typedef float f32x2 __attribute__((ext_vector_type(2)));
typedef const __attribute__((address_space(1))) unsigned ag_u32;  // global
typedef __attribute__((address_space(3))) unsigned al_u32;        // LDS

// workspace layout (bytes from ws start)
#define OFF_XB  0u               // bf16 [8192][128] = 2 MiB (row-granule-XOR-swizzled)
#define OFF_GS  2097152u         // f32 [16][8192][4]  col-hist partials, bins 3..6 (2 MiB)
#define OFF_GSP 4194304u         // f32 [16][8192][4]  pos-hist partials (2 MiB)
#define OFF_GA  6291456u         // q16 [8192][12] all-hist corrections (atomic)
#define OFF_GAP 6684672u         // q16 [8192][12] pos-hist corrections (atomic)
#define OFF_DB  7077888u         // u32 [128] per-strip done counters
#define OFF_AC  7078400u         // float[2] accum + u32 done
#define ZERO_BYTES 786960u       // OFF_GA .. end (16B multiple); gS/gSp fully overwritten

__device__ inline unsigned short f2bf(float f) {
  unsigned u = __float_as_uint(f);
  u += 0x7fffu + ((u >> 16) & 1u);   // round-to-nearest-even
  return (unsigned short)(u >> 16);
}
// v_med3_f32 with inline consts: 1-instr clamp (no v_pk_min/max_f32 on gfx950)
__device__ inline float clamp01(float x) { return __builtin_amdgcn_fmed3f(x, 0.f, 1.f); }

// ---- prep: fp32->bf16 convert into XOR-swizzled layout + zero correction bufs ----
__global__ __launch_bounds__(256) void prep_kernel(const float* __restrict__ x,
                                                   unsigned short* __restrict__ xb,
                                                   uint4* __restrict__ zbase) {
  const int gid = blockIdx.x * 256 + threadIdx.x;   // 131072 threads: row*16+granule
  const int row = gid >> 4, g = gid & 15;
  const float4 v0 = reinterpret_cast<const float4*>(x)[row * 32 + g * 2];
  const float4 v1 = reinterpret_cast<const float4*>(x)[row * 32 + g * 2 + 1];
  uint4 o;
  o.x = (unsigned)f2bf(v0.x) | ((unsigned)f2bf(v0.y) << 16);
  o.y = (unsigned)f2bf(v0.z) | ((unsigned)f2bf(v0.w) << 16);
  o.z = (unsigned)f2bf(v1.x) | ((unsigned)f2bf(v1.y) << 16);
  o.w = (unsigned)f2bf(v1.z) | ((unsigned)f2bf(v1.w) << 16);
  reinterpret_cast<uint4*>(xb)[row * 16 + (g ^ (row & 7))] = o;
  if (gid < (int)(ZERO_BYTES / 16u)) zbase[gid] = make_uint4(0u, 0u, 0u, 0u);
}

// ---- main: fixed 16-col B frags per wave, streamed 32-row LDS panels ----
// Symmetry: per-row hist == per-col hist, so each lane accumulates the hist of
// ONE column (its l16 col) across its 4 acc rows -> packed C01/C23, Cp01/Cp23.
// gS/gSp are plain per-row-chunk float4 stores (16 slots).  The 16th block to
// finish a column strip (doneBx counter) runs the fused epilogue for its 64
// cols: label hist + partial sums + corrections + AP + loss reduction.
__global__ __launch_bounds__(256, 8) void fastap_main_kernel(
    const unsigned short* __restrict__ xb,
    const int* __restrict__ labels,
    float* __restrict__ gS, float* __restrict__ gSp,
    unsigned* __restrict__ gA, unsigned* __restrict__ gAp,
    unsigned* __restrict__ doneBx,
    float* __restrict__ accum, unsigned* __restrict__ done,
    float* __restrict__ out) {
  __shared__ __align__(16) unsigned short sA[2][32 * 128];  // 2 x 8KB row panels
  __shared__ int sLab[ROWCHUNK];                            // this chunk's row labels
  __shared__ int sFinal;

  const int tid  = threadIdx.x;
  const int wave = tid >> 6;
  const int lane = tid & 63;
  const int l16  = lane & 15;
  const int quad = lane >> 4;
  const int colBase  = blockIdx.x * 64;       // 128 col strips
  const int rowChunk = blockIdx.y * ROWCHUNK; // 16 row chunks

  if (tid < ROWCHUNK / 4)
    reinterpret_cast<int4*>(sLab)[tid] =
        reinterpret_cast<const int4*>(labels + rowChunk)[tid];

  // fixed B fragments: this wave's 16 cols, K=128 (jcol&7 == l16&7)
  const int jcol = colBase + wave * 16 + l16;
  bf16x8 bfr[4];
  #pragma unroll
  for (int kb = 0; kb < 4; ++kb) {
    const int pg = (kb * 4 + quad) ^ (l16 & 7);
    bfr[kb] = *reinterpret_cast<const bf16x8*>(&xb[jcol * 128 + pg * 8]);
  }
  const int labj = labels[jcol];

  f32x2 C01 = {0.f, 0.f}, C23 = {0.f, 0.f};
  f32x2 Cp01 = {0.f, 0.f}, Cp23 = {0.f, 0.f};

  // A-frag ds_read offsets within a 16-row sub-panel (row&7 == l16&7)
  int aOff[4];
  #pragma unroll
  for (int kb = 0; kb < 4; ++kb)
    aOff[kb] = l16 * 128 + (((kb * 4 + quad) ^ (l16 & 7)) << 3);

  // stage panel p's 32 rows (8KB) into buffer b: 2 x 16B per thread
  const unsigned short* xrb = xb + rowChunk * 128;
  auto stage = [&](int p, int b) {
    const unsigned short* src = xrb + p * (32 * 128);
    __builtin_amdgcn_global_load_lds((ag_u32*)(src + tid * 8),
                                     (al_u32*)(&sA[b][tid * 8]), 16, 0, 0);
    __builtin_amdgcn_global_load_lds((ag_u32*)(src + (tid + 256) * 8),
                                     (al_u32*)(&sA[b][(tid + 256) * 8]), 16, 0, 0);
  };

  // one 16-row x 16-col tile; lcr = row offset within chunk (mult of 16)
  auto tile16 = [&](const unsigned short* ap, int lcr) {
    const int4 lr = *reinterpret_cast<const int4*>(&sLab[lcr + quad * 4]);
    bf16x8 a0 = *reinterpret_cast<const bf16x8*>(&ap[aOff[0]]);
    bf16x8 a1 = *reinterpret_cast<const bf16x8*>(&ap[aOff[1]]);
    bf16x8 a2 = *reinterpret_cast<const bf16x8*>(&ap[aOff[2]]);
    bf16x8 a3 = *reinterpret_cast<const bf16x8*>(&ap[aOff[3]]);
    f32x4 acc = {0.f, 0.f, 0.f, 0.f};    // single chain: 8 waves/SIMD hide latency
    acc = __builtin_amdgcn_mfma_f32_16x16x32_bf16(a0, bfr[0], acc, 0, 0, 0);
    acc = __builtin_amdgcn_mfma_f32_16x16x32_bf16(a1, bfr[1], acc, 0, 0, 0);
    acc = __builtin_amdgcn_mfma_f32_16x16x32_bf16(a2, bfr[2], acc, 0, 0, 0);
    acc = __builtin_amdgcn_mfma_f32_16x16x32_bf16(a3, bfr[3], acc, 0, 0, 0);

    const int labr[4] = {lr.x, lr.y, lr.z, lr.w};
    // fast path: pk_fma ramps + med3 clamps. Register bins 3..6 are EXACT
    // for all t: H[k] = clamp01(5a + (k-4)).
    #pragma unroll
    for (int r = 0; r < 4; ++r) {              // D: row = quad*4+r, col = l16
      const float a = acc[r];                  // cos(i, jcol)
      const float pm = (labr[r] == labj) ? 1.f : 0.f;  // diag fixed in rare path
      const f32x2 av = {a, a}, p2 = {pm, pm};
      f32x2 d01 = __builtin_elementwise_fma(av, (f32x2){5.f, 5.f},
                                            (f32x2){-1.f, 0.f});
      f32x2 d23 = __builtin_elementwise_fma(av, (f32x2){5.f, 5.f},
                                            (f32x2){1.f, 2.f});
      d01 = (f32x2){clamp01(d01.x), clamp01(d01.y)};
      d23 = (f32x2){clamp01(d23.x), clamp01(d23.y)};
      C01 += d01; C23 += d23;
      Cp01 = __builtin_elementwise_fma(p2, d01, Cp01);
      Cp23 = __builtin_elementwise_fma(p2, d23, Cp23);
    }

    // one rare check per 4 pairs (abs modifiers are free on v_max)
    const float mabs = fmaxf(fmaxf(fabsf(acc[0]), fabsf(acc[1])),
                             fmaxf(fabsf(acc[2]), fabsf(acc[3])));
    if (__builtin_expect(mabs > 0.4f, 0)) {
      #pragma unroll
      for (int r = 0; r < 4; ++r) {
        const float a = acc[r];
        if (fabsf(a) <= 0.4f) continue;
        const int i = rowChunk + lcr + quad * 4 + r;
        // recompute (bit-identical to fast path)
        const float d0 = clamp01(fmaf(a, 5.f, -1.f));
        const float d1 = clamp01(a * 5.f);
        const float d2 = clamp01(fmaf(a, 5.f, 1.f));
        const float d3 = clamp01(fmaf(a, 5.f, 2.f));
        if (i == jcol) {
          // diagonal: cancel fast contributions (pm was 1) + bins>=7 base (+1)
          C01 -= (f32x2){d0, d1};  C23 -= (f32x2){d2, d3};
          Cp01 -= (f32x2){d0, d1}; Cp23 -= (f32x2){d2, d3};
          #pragma unroll
          for (int k = 7; k <= 10; ++k)
            atomicAdd(&gA[jcol * AROW + k], (unsigned)(-65536));
        } else {
          const bool isPos = (labr[r] == labj);
          const float t = fmaf(a, -5.f, 5.f);
          #pragma unroll
          for (int k = 0; k <= 2; ++k) {       // assumed cumulative 0
            const float v = clamp01((float)(k + 1) - t);
            const int q = (int)(v * 65536.f + 0.5f);
            if (q) {
              atomicAdd(&gA[jcol * AROW + k], (unsigned)q);
              if (isPos) atomicAdd(&gAp[jcol * AROW + k], (unsigned)q);
            }
          }
          #pragma unroll
          for (int k = 7; k <= 10; ++k) {      // assumed cumulative 1
            const float v = clamp01((float)(k + 1) - t) - 1.f;
            const int q = (int)(v * 65536.f - 0.5f);
            if (q) {
              atomicAdd(&gA[jcol * AROW + k], (unsigned)q);
              if (isPos) atomicAdd(&gAp[jcol * AROW + k], (unsigned)q);
            }
          }
        }
      }
    }
  };

  stage(0, 0);
  __syncthreads();             // sLab visible + panel 0 drained

  #pragma unroll 1
  for (int p = 0; p < NPANEL; ++p) {
    const int cur = p & 1;
    if (p + 1 < NPANEL) stage(p + 1, cur ^ 1);   // async DMA behind this panel
    tile16(&sA[cur][0],        p * 32);
    tile16(&sA[cur][16 * 128], p * 32 + 16);
    __syncthreads();
  }

  // reduce across the 4 quads sharing each column (lane ^16, ^32)
  #pragma unroll
  for (int m = 16; m < 64; m <<= 1) {
    C01.x  += __shfl_xor(C01.x,  m, 64); C01.y  += __shfl_xor(C01.y,  m, 64);
    C23.x  += __shfl_xor(C23.x,  m, 64); C23.y  += __shfl_xor(C23.y,  m, 64);
    Cp01.x += __shfl_xor(Cp01.x, m, 64); Cp01.y += __shfl_xor(Cp01.y, m, 64);
    Cp23.x += __shfl_xor(Cp23.x, m, 64); Cp23.y += __shfl_xor(Cp23.y, m, 64);
  }

  if (quad == 0) {
    const int slot = blockIdx.y;                 // 16 partial slots, no atomics
    const float4 cv  = make_float4(C01.x,  C01.y,  C23.x,  C23.y);
    const float4 cpv = make_float4(Cp01.x, Cp01.y, Cp23.x, Cp23.y);
    reinterpret_cast<float4*>(gS)[slot * NS + jcol]  = cv;
    reinterpret_cast<float4*>(gSp)[slot * NS + jcol] = cpv;
  }

  // ---- fused finalize: 16th block of this column strip does the epilogue ----
  __syncthreads();             // all stores at L2 (vmcnt drained per thread)
  if (tid == 0) {
    __threadfence();           // buffer_wbl2: flush this XCD's L2 to device scope
    sFinal = (atomicAdd(&doneBx[blockIdx.x], 1u) == 15u);
  }
  __syncthreads();
  if (!sFinal) return;

  // label histogram (np = count[label]-1); sLab reused as 128 counters
  if (tid < 128) sLab[tid] = 0;
  __syncthreads();
  for (int idx = tid; idx < NS; idx += 256)
    atomicAdd(&sLab[labels[idx]], 1);
  __syncthreads();

  const int c   = tid >> 2;                      // 64 cols, 4 threads each
  const int sub = tid & 3;
  const int col = colBase + c;
  const float4* gS4  = reinterpret_cast<const float4*>(gS);
  const float4* gSp4 = reinterpret_cast<const float4*>(gSp);
  float4 Cs  = make_float4(0.f, 0.f, 0.f, 0.f);
  float4 Cps = make_float4(0.f, 0.f, 0.f, 0.f);
  #pragma unroll
  for (int s4 = 0; s4 < 4; ++s4) {               // this sub's 4 of 16 slots
    const float4 u = gS4[(sub * 4 + s4) * NS + col];
    const float4 v = gSp4[(sub * 4 + s4) * NS + col];
    Cs.x += u.x; Cs.y += u.y; Cs.z += u.z; Cs.w += u.w;
    Cps.x += v.x; Cps.y += v.y; Cps.z += v.z; Cps.w += v.w;
  }
  #pragma unroll
  for (int m = 1; m < 4; m <<= 1) {              // combine the 4 subs (same wave)
    Cs.x += __shfl_xor(Cs.x, m, 64);   Cs.y += __shfl_xor(Cs.y, m, 64);
    Cs.z += __shfl_xor(Cs.z, m, 64);   Cs.w += __shfl_xor(Cs.w, m, 64);
    Cps.x += __shfl_xor(Cps.x, m, 64); Cps.y += __shfl_xor(Cps.y, m, 64);
    Cps.z += __shfl_xor(Cps.z, m, 64); Cps.w += __shfl_xor(Cps.w, m, 64);
  }

  float ap = 0.f, val = 0.f;
  if (sub == 0) {
    const int np = sLab[labels[col]] - 1;        // N_pos = classCount - 1
    const float CsA[4]  = {Cs.x, Cs.y, Cs.z, Cs.w};
    const float CpsA[4] = {Cps.x, Cps.y, Cps.z, Cps.w};
    float HpPrev = 0.f;
    #pragma unroll
    for (int b = 0; b <= 10; ++b) {
      const float baseH  = (b < 3) ? 0.f : (b < 7) ? CsA[b - 3]  : 8192.f;
      const float basePp = (b < 3) ? 0.f : (b < 7) ? CpsA[b - 3] : (float)np;
      const float H  = baseH  + (float)(int)gA[col * AROW + b]  * INV64K;
      const float Hp = basePp + (float)(int)gAp[col * AROW + b] * INV64K;
      const float hp = Hp - HpPrev;
      HpPrev = Hp;
      if (H > 1e-6f) ap += hp * Hp / H;
    }
    if (np > 0) { ap /= (float)np; val = 1.f; } else ap = 0.f;
  }

  float* sa = reinterpret_cast<float*>(&sA[0][0]);
  float* sv = sa + 256;
  sa[tid] = ap; sv[tid] = val;
  __syncthreads();
  for (int s = 128; s > 0; s >>= 1) {
    if (tid < s) { sa[tid] += sa[tid + s]; sv[tid] += sv[tid + s]; }
    __syncthreads();
  }
  if (tid == 0) {
    atomicAdd(&accum[0], sa[0]);
    atomicAdd(&accum[1], sv[0]);
    __threadfence();
    const unsigned prev = atomicAdd(done, 1u);
    if (prev == 127u) {                          // last of 128 strip finalizers
      const float a2 = atomicAdd(&accum[0], 0.f);   // coherent reads
      const float c2 = atomicAdd(&accum[1], 0.f);
      out[0] = 1.f - (c2 > 0.f ? a2 / c2 : 0.f);
    }
  }
}

extern "C" void kernel_launch(void* const* d_in, const int* in_sizes, int n_in,
                              void* d_out, int out_size, void* d_ws, size_t ws_size,
                              hipStream_t stream) {
  const float* x      = (const float*)d_in[0];
  const int*   labels = (const int*)d_in[1];
  float* out = (float*)d_out;

  char* ws = (char*)d_ws;
  unsigned short* xb = (unsigned short*)(ws + OFF_XB);
  float*    gS    = (float*)(ws + OFF_GS);
  float*    gSp   = (float*)(ws + OFF_GSP);
  unsigned* gA    = (unsigned*)(ws + OFF_GA);
  unsigned* gAp   = (unsigned*)(ws + OFF_GAP);
  unsigned* dBx   = (unsigned*)(ws + OFF_DB);
  float*    accum = (float*)(ws + OFF_AC);
  unsigned* done  = (unsigned*)(ws + OFF_AC + 8);

  prep_kernel<<<512, 256, 0, stream>>>(x, xb, (uint4*)(ws + OFF_GA));
  fastap_main_kernel<<<dim3(NS / 64, NS / ROWCHUNK), 256, 0, stream>>>(
      xb, labels, gS, gSp, gA, gAp, dBx, accum, done, out);
}

// Round 4
// 113.846 us; speedup vs baseline: 1.3556x; 1.3556x over previous
//
#include <hip/hip_runtime.h>

#define NS 8192
#define EMBED 128
#define ROWCHUNK 512             // grid.y = 16 chunks of 512 rows
#define NPANEL (ROWCHUNK / 32)   // 16 panels of 32 rows
#define AROW 12                  // correction-hist row stride (11 bins + 1 pad)
#define INV64K (1.0f / 65536.0f)

typedef __bf16 bf16x8 __attribute__((ext_vector_type(8)));
typedef float f32x4 __attribute__((ext_vector_type(4)));
typedef float f32x2 __attribute__((ext_vector_type(2)));
typedef const __attribute__((address_space(1))) unsigned ag_u32;  // global
typedef __attribute__((address_space(3))) unsigned al_u32;        // LDS

// workspace layout (bytes from ws start)
#define OFF_XB  0u               // bf16 [8192][128] = 2 MiB (row-granule-XOR-swizzled)
#define OFF_GS  2097152u         // q16 u32 [8192][4]  col-hist bins 3..6 (128 KiB)
#define OFF_GSP 2228224u         // q16 u32 [8192][4]  pos-hist bins 3..6 (128 KiB)
#define OFF_GA  2359296u         // q16 u32 [8192][12] all-hist corrections (384 KiB)
#define OFF_GAP 2752512u         // q16 u32 [8192][12] pos-hist corrections (384 KiB)
#define OFF_DB  3145728u         // u32 [128] per-strip done counters
#define OFF_AC  3146240u         // float[2] accum + u32 done
#define ZERO_BYTES 1049104u      // OFF_GS .. OFF_AC+16 (16B multiple)

__device__ inline unsigned short f2bf(float f) {
  unsigned u = __float_as_uint(f);
  u += 0x7fffu + ((u >> 16) & 1u);   // round-to-nearest-even
  return (unsigned short)(u >> 16);
}
// v_med3_f32 with inline consts: 1-instr clamp (no v_pk_min/max_f32 on gfx950)
__device__ inline float clamp01(float x) { return __builtin_amdgcn_fmed3f(x, 0.f, 1.f); }

// ---- prep: fp32->bf16 convert into XOR-swizzled layout + zero accumulators ----
__global__ __launch_bounds__(256) void prep_kernel(const float* __restrict__ x,
                                                   unsigned short* __restrict__ xb,
                                                   uint4* __restrict__ zbase) {
  const int gid = blockIdx.x * 256 + threadIdx.x;   // 131072 threads: row*16+granule
  const int row = gid >> 4, g = gid & 15;
  const float4 v0 = reinterpret_cast<const float4*>(x)[row * 32 + g * 2];
  const float4 v1 = reinterpret_cast<const float4*>(x)[row * 32 + g * 2 + 1];
  uint4 o;
  o.x = (unsigned)f2bf(v0.x) | ((unsigned)f2bf(v0.y) << 16);
  o.y = (unsigned)f2bf(v0.z) | ((unsigned)f2bf(v0.w) << 16);
  o.z = (unsigned)f2bf(v1.x) | ((unsigned)f2bf(v1.y) << 16);
  o.w = (unsigned)f2bf(v1.z) | ((unsigned)f2bf(v1.w) << 16);
  reinterpret_cast<uint4*>(xb)[row * 16 + (g ^ (row & 7))] = o;
  if (gid < (int)(ZERO_BYTES / 16u)) zbase[gid] = make_uint4(0u, 0u, 0u, 0u);
}

// ---- main: fixed 16-col B frags per wave, streamed 32-row LDS panels ----
// Symmetry: per-row hist == per-col hist, so each lane accumulates the hist of
// ONE column (its l16 col) across its 4 acc rows -> packed C01/C23, Cp01/Cp23.
// ALL cross-block-visible writes are device-scope atomics (coherent at the LLC
// once vmcnt-retired) -> no __threadfence/buffer_wbl2 anywhere in the hot path.
// The 16th block of a column strip (relaxed doneBx counter, release ordering
// supplied by the preceding __syncthreads' vmcnt drain) runs the fused
// epilogue for its 64 cols, fetching partials via atomicAdd(p,0) RMWs.
__global__ __launch_bounds__(256, 8) void fastap_main_kernel(
    const unsigned short* __restrict__ xb,
    const int* __restrict__ labels,
    unsigned* __restrict__ gS, unsigned* __restrict__ gSp,
    unsigned* __restrict__ gA, unsigned* __restrict__ gAp,
    unsigned* __restrict__ doneBx,
    float* __restrict__ accum, unsigned* __restrict__ done,
    float* __restrict__ out) {
  __shared__ __align__(16) unsigned short sA[2][32 * 128];  // 2 x 8KB row panels
  __shared__ int sLab[ROWCHUNK];                            // this chunk's row labels
  __shared__ int sFinal;

  const int tid  = threadIdx.x;
  const int wave = tid >> 6;
  const int lane = tid & 63;
  const int l16  = lane & 15;
  const int quad = lane >> 4;
  const int colBase  = blockIdx.x * 64;       // 128 col strips
  const int rowChunk = blockIdx.y * ROWCHUNK; // 16 row chunks

  if (tid < ROWCHUNK / 4)
    reinterpret_cast<int4*>(sLab)[tid] =
        reinterpret_cast<const int4*>(labels + rowChunk)[tid];

  // fixed B fragments: this wave's 16 cols, K=128 (jcol&7 == l16&7)
  const int jcol = colBase + wave * 16 + l16;
  bf16x8 bfr[4];
  #pragma unroll
  for (int kb = 0; kb < 4; ++kb) {
    const int pg = (kb * 4 + quad) ^ (l16 & 7);
    bfr[kb] = *reinterpret_cast<const bf16x8*>(&xb[jcol * 128 + pg * 8]);
  }
  const int labj = labels[jcol];

  f32x2 C01 = {0.f, 0.f}, C23 = {0.f, 0.f};
  f32x2 Cp01 = {0.f, 0.f}, Cp23 = {0.f, 0.f};

  // A-frag ds_read offsets within a 16-row sub-panel (row&7 == l16&7)
  int aOff[4];
  #pragma unroll
  for (int kb = 0; kb < 4; ++kb)
    aOff[kb] = l16 * 128 + (((kb * 4 + quad) ^ (l16 & 7)) << 3);

  // stage panel p's 32 rows (8KB) into buffer b: 2 x 16B per thread
  const unsigned short* xrb = xb + rowChunk * 128;
  auto stage = [&](int p, int b) {
    const unsigned short* src = xrb + p * (32 * 128);
    __builtin_amdgcn_global_load_lds((ag_u32*)(src + tid * 8),
                                     (al_u32*)(&sA[b][tid * 8]), 16, 0, 0);
    __builtin_amdgcn_global_load_lds((ag_u32*)(src + (tid + 256) * 8),
                                     (al_u32*)(&sA[b][(tid + 256) * 8]), 16, 0, 0);
  };

  // one 16-row x 16-col tile; lcr = row offset within chunk (mult of 16)
  auto tile16 = [&](const unsigned short* ap, int lcr) {
    const int4 lr = *reinterpret_cast<const int4*>(&sLab[lcr + quad * 4]);
    bf16x8 a0 = *reinterpret_cast<const bf16x8*>(&ap[aOff[0]]);
    bf16x8 a1 = *reinterpret_cast<const bf16x8*>(&ap[aOff[1]]);
    bf16x8 a2 = *reinterpret_cast<const bf16x8*>(&ap[aOff[2]]);
    bf16x8 a3 = *reinterpret_cast<const bf16x8*>(&ap[aOff[3]]);
    f32x4 acc = {0.f, 0.f, 0.f, 0.f};    // single chain: 8 waves/SIMD hide latency
    acc = __builtin_amdgcn_mfma_f32_16x16x32_bf16(a0, bfr[0], acc, 0, 0, 0);
    acc = __builtin_amdgcn_mfma_f32_16x16x32_bf16(a1, bfr[1], acc, 0, 0, 0);
    acc = __builtin_amdgcn_mfma_f32_16x16x32_bf16(a2, bfr[2], acc, 0, 0, 0);
    acc = __builtin_amdgcn_mfma_f32_16x16x32_bf16(a3, bfr[3], acc, 0, 0, 0);

    const int labr[4] = {lr.x, lr.y, lr.z, lr.w};
    // fast path: pk_fma ramps + med3 clamps. Register bins 3..6 are EXACT
    // for all t: H[k] = clamp01(5a + (k-4)).
    #pragma unroll
    for (int r = 0; r < 4; ++r) {              // D: row = quad*4+r, col = l16
      const float a = acc[r];                  // cos(i, jcol)
      const float pm = (labr[r] == labj) ? 1.f : 0.f;  // diag fixed in rare path
      const f32x2 av = {a, a}, p2 = {pm, pm};
      f32x2 d01 = __builtin_elementwise_fma(av, (f32x2){5.f, 5.f},
                                            (f32x2){-1.f, 0.f});
      f32x2 d23 = __builtin_elementwise_fma(av, (f32x2){5.f, 5.f},
                                            (f32x2){1.f, 2.f});
      d01 = (f32x2){clamp01(d01.x), clamp01(d01.y)};
      d23 = (f32x2){clamp01(d23.x), clamp01(d23.y)};
      C01 += d01; C23 += d23;
      Cp01 = __builtin_elementwise_fma(p2, d01, Cp01);
      Cp23 = __builtin_elementwise_fma(p2, d23, Cp23);
    }

    // one rare check per 4 pairs (abs modifiers are free on v_max)
    const float mabs = fmaxf(fmaxf(fabsf(acc[0]), fabsf(acc[1])),
                             fmaxf(fabsf(acc[2]), fabsf(acc[3])));
    if (__builtin_expect(mabs > 0.4f, 0)) {
      #pragma unroll
      for (int r = 0; r < 4; ++r) {
        const float a = acc[r];
        if (fabsf(a) <= 0.4f) continue;
        const int i = rowChunk + lcr + quad * 4 + r;
        // recompute (bit-identical to fast path)
        const float d0 = clamp01(fmaf(a, 5.f, -1.f));
        const float d1 = clamp01(a * 5.f);
        const float d2 = clamp01(fmaf(a, 5.f, 1.f));
        const float d3 = clamp01(fmaf(a, 5.f, 2.f));
        if (i == jcol) {
          // diagonal: cancel fast contributions (pm was 1) + bins>=7 base (+1)
          C01 -= (f32x2){d0, d1};  C23 -= (f32x2){d2, d3};
          Cp01 -= (f32x2){d0, d1}; Cp23 -= (f32x2){d2, d3};
          #pragma unroll
          for (int k = 7; k <= 10; ++k)
            atomicAdd(&gA[jcol * AROW + k], (unsigned)(-65536));
        } else {
          const bool isPos = (labr[r] == labj);
          const float t = fmaf(a, -5.f, 5.f);
          #pragma unroll
          for (int k = 0; k <= 2; ++k) {       // assumed cumulative 0
            const float v = clamp01((float)(k + 1) - t);
            const int q = (int)(v * 65536.f + 0.5f);
            if (q) {
              atomicAdd(&gA[jcol * AROW + k], (unsigned)q);
              if (isPos) atomicAdd(&gAp[jcol * AROW + k], (unsigned)q);
            }
          }
          #pragma unroll
          for (int k = 7; k <= 10; ++k) {      // assumed cumulative 1
            const float v = clamp01((float)(k + 1) - t) - 1.f;
            const int q = (int)(v * 65536.f - 0.5f);
            if (q) {
              atomicAdd(&gA[jcol * AROW + k], (unsigned)q);
              if (isPos) atomicAdd(&gAp[jcol * AROW + k], (unsigned)q);
            }
          }
        }
      }
    }
  };

  stage(0, 0);
  __syncthreads();             // sLab visible + panel 0 drained

  #pragma unroll 1
  for (int p = 0; p < NPANEL; ++p) {
    const int cur = p & 1;
    if (p + 1 < NPANEL) stage(p + 1, cur ^ 1);   // async DMA behind this panel
    tile16(&sA[cur][0],        p * 32);
    tile16(&sA[cur][16 * 128], p * 32 + 16);
    __syncthreads();
  }

  // reduce across the 4 quads sharing each column (lane ^16, ^32)
  #pragma unroll
  for (int m = 16; m < 64; m <<= 1) {
    C01.x  += __shfl_xor(C01.x,  m, 64); C01.y  += __shfl_xor(C01.y,  m, 64);
    C23.x  += __shfl_xor(C23.x,  m, 64); C23.y  += __shfl_xor(C23.y,  m, 64);
    Cp01.x += __shfl_xor(Cp01.x, m, 64); Cp01.y += __shfl_xor(Cp01.y, m, 64);
    Cp23.x += __shfl_xor(Cp23.x, m, 64); Cp23.y += __shfl_xor(Cp23.y, m, 64);
  }

  if (quad == 0) {
    const float Cv[4]  = {C01.x, C01.y, C23.x, C23.y};
    const float Cpv[4] = {Cp01.x, Cp01.y, Cp23.x, Cp23.y};
    #pragma unroll
    for (int k = 0; k < 4; ++k) {       // q16 device atomics -> coherent at LLC
      atomicAdd(&gS[jcol * 4 + k],  (unsigned)(int)lrintf(Cv[k]  * 65536.f));
      atomicAdd(&gSp[jcol * 4 + k], (unsigned)(int)lrintf(Cpv[k] * 65536.f));
    }
  }

  // ---- fused finalize: 16th block of this column strip does the epilogue ----
  // Release: __syncthreads drains every lane's vmcnt -> all this block's
  // atomics are globally performed before tid0's counter bump issues.
  __syncthreads();
  if (tid == 0) {
    __asm__ volatile("" ::: "memory");   // no wbl2: all shared data is atomic
    sFinal = (atomicAdd(&doneBx[blockIdx.x], 1u) == 15u);
  }
  __syncthreads();
  if (!sFinal) return;

  // label histogram (np = count[label]-1); sLab reused as 128 counters
  if (tid < 128) sLab[tid] = 0;
  __syncthreads();
  for (int idx = tid; idx < NS; idx += 256)
    atomicAdd(&sLab[labels[idx]], 1);
  __syncthreads();

  if (tid < 64) {                       // one col per lane of wave 0
    const int col = colBase + tid;
    const int np = sLab[labels[col]] - 1;        // N_pos = classCount - 1

    // fetch partials via RMW-at-LLC (immune to any stale-L2 scenario)
    unsigned gsv[4], gspv[4], gav[11], gapv[11];
    #pragma unroll
    for (int k = 0; k < 4; ++k) {
      gsv[k]  = atomicAdd(&gS[col * 4 + k], 0u);
      gspv[k] = atomicAdd(&gSp[col * 4 + k], 0u);
    }
    #pragma unroll
    for (int b = 0; b < 11; ++b) {
      gav[b]  = atomicAdd(&gA[col * AROW + b], 0u);
      gapv[b] = atomicAdd(&gAp[col * AROW + b], 0u);
    }

    float ap = 0.f, val = 0.f, HpPrev = 0.f;
    #pragma unroll
    for (int b = 0; b <= 10; ++b) {
      const float baseH  = (b < 3) ? 0.f
                         : (b < 7) ? (float)(int)gsv[b - 3]  * INV64K : 8192.f;
      const float basePp = (b < 3) ? 0.f
                         : (b < 7) ? (float)(int)gspv[b - 3] * INV64K : (float)np;
      const float H  = baseH  + (float)(int)gav[b]  * INV64K;
      const float Hp = basePp + (float)(int)gapv[b] * INV64K;
      const float hp = Hp - HpPrev;
      HpPrev = Hp;
      if (H > 1e-6f) ap += hp * Hp / H;
    }
    if (np > 0) { ap /= (float)np; val = 1.f; } else ap = 0.f;

    #pragma unroll
    for (int m = 1; m < 64; m <<= 1) {  // wave-0 shuffle reduce over 64 cols
      ap  += __shfl_xor(ap,  m, 64);
      val += __shfl_xor(val, m, 64);
    }
    if (tid == 0) {
      atomicAdd(&accum[0], ap);
      atomicAdd(&accum[1], val);
      __builtin_amdgcn_s_waitcnt(0);     // accum adds performed before bump
      __asm__ volatile("" ::: "memory");
      const unsigned prev = atomicAdd(done, 1u);
      if (prev == 127u) {                // last of 128 strip finalizers
        const float a2 = atomicAdd(&accum[0], 0.f);   // RMW reads at LLC
        const float c2 = atomicAdd(&accum[1], 0.f);
        out[0] = 1.f - (c2 > 0.f ? a2 / c2 : 0.f);
      }
    }
  }
}

extern "C" void kernel_launch(void* const* d_in, const int* in_sizes, int n_in,
                              void* d_out, int out_size, void* d_ws, size_t ws_size,
                              hipStream_t stream) {
  const float* x      = (const float*)d_in[0];
  const int*   labels = (const int*)d_in[1];
  float* out = (float*)d_out;

  char* ws = (char*)d_ws;
  unsigned short* xb = (unsigned short*)(ws + OFF_XB);
  unsigned* gS    = (unsigned*)(ws + OFF_GS);
  unsigned* gSp   = (unsigned*)(ws + OFF_GSP);
  unsigned* gA    = (unsigned*)(ws + OFF_GA);
  unsigned* gAp   = (unsigned*)(ws + OFF_GAP);
  unsigned* dBx   = (unsigned*)(ws + OFF_DB);
  float*    accum = (float*)(ws + OFF_AC);
  unsigned* done  = (unsigned*)(ws + OFF_AC + 8);

  prep_kernel<<<512, 256, 0, stream>>>(x, xb, (uint4*)(ws + OFF_GS));
  fastap_main_kernel<<<dim3(NS / 64, NS / ROWCHUNK), 256, 0, stream>>>(
      xb, labels, gS, gSp, gA, gAp, dBx, accum, done, out);
}

// Round 5
// 112.517 us; speedup vs baseline: 1.3716x; 1.0118x over previous
//
#include <hip/hip_runtime.h>

#define NS 8192
#define EMBED 128
#define ROWCHUNK 512             // grid.y = 16 chunks of 512 rows
#define NPANEL (ROWCHUNK / 32)   // 16 panels of 32 rows
#define AROW 12                  // correction-hist row stride (11 bins + 1 pad)
#define INV64K (1.0f / 65536.0f)

typedef __bf16 bf16x8 __attribute__((ext_vector_type(8)));
typedef float f32x4 __attribute__((ext_vector_type(4)));
typedef float f32x2 __attribute__((ext_vector_type(2)));
typedef const __attribute__((address_space(1))) unsigned ag_u32;  // global
typedef __attribute__((address_space(3))) unsigned al_u32;        // LDS

// workspace layout (bytes from ws start)
#define OFF_XB  0u               // bf16 [8192][128] = 2 MiB (row-granule-XOR-swizzled)
#define OFF_GS  2097152u         // f32 [16][8192][4]  col-hist partials, bins 3..6 (2 MiB)
#define OFF_GSP 4194304u         // f32 [16][8192][4]  pos-hist partials (2 MiB)
#define OFF_GA  6291456u         // q16 u32 [8192][12] all-hist corrections (384 KiB)
#define OFF_GAP 6684672u         // q16 u32 [8192][12] pos-hist corrections (384 KiB)
#define OFF_CS  7077888u         // u32 [128][128] per-strip class counts (64 KiB)
#define OFF_DB  7143424u         // u32 [128] per-strip done counters
#define OFF_AC  7143936u         // float[2] accum + u32 done
#define ZERO_BYTES 852496u       // OFF_GA .. OFF_AC+16 (16B multiple)

__device__ inline unsigned short f2bf(float f) {
  unsigned u = __float_as_uint(f);
  u += 0x7fffu + ((u >> 16) & 1u);   // round-to-nearest-even
  return (unsigned short)(u >> 16);
}
// v_med3_f32 with inline consts: 1-instr clamp (no v_pk_min/max_f32 on gfx950)
__device__ inline float clamp01(float x) { return __builtin_amdgcn_fmed3f(x, 0.f, 1.f); }

// device-scope (agent) plain stores/loads: coherent at the LLC, no RMW, no wbl2
__device__ inline void st8_dev(float* p, float x, float y) {
  unsigned long long u =
      ((unsigned long long)__float_as_uint(y) << 32) | __float_as_uint(x);
  __hip_atomic_store(reinterpret_cast<unsigned long long*>(p), u,
                     __ATOMIC_RELAXED, __HIP_MEMORY_SCOPE_AGENT);
}
__device__ inline float2 ld8_dev(const float* p) {
  unsigned long long u =
      __hip_atomic_load(reinterpret_cast<const unsigned long long*>(p),
                        __ATOMIC_RELAXED, __HIP_MEMORY_SCOPE_AGENT);
  return make_float2(__uint_as_float((unsigned)u),
                     __uint_as_float((unsigned)(u >> 32)));
}
__device__ inline unsigned ld4_dev(const unsigned* p) {
  return __hip_atomic_load(p, __ATOMIC_RELAXED, __HIP_MEMORY_SCOPE_AGENT);
}

// ---- prep: fp32->bf16 convert into XOR-swizzled layout + zero accumulators ----
__global__ __launch_bounds__(256) void prep_kernel(const float* __restrict__ x,
                                                   unsigned short* __restrict__ xb,
                                                   uint4* __restrict__ zbase) {
  const int gid = blockIdx.x * 256 + threadIdx.x;   // 131072 threads: row*16+granule
  const int row = gid >> 4, g = gid & 15;
  const float4 v0 = reinterpret_cast<const float4*>(x)[row * 32 + g * 2];
  const float4 v1 = reinterpret_cast<const float4*>(x)[row * 32 + g * 2 + 1];
  uint4 o;
  o.x = (unsigned)f2bf(v0.x) | ((unsigned)f2bf(v0.y) << 16);
  o.y = (unsigned)f2bf(v0.z) | ((unsigned)f2bf(v0.w) << 16);
  o.z = (unsigned)f2bf(v1.x) | ((unsigned)f2bf(v1.y) << 16);
  o.w = (unsigned)f2bf(v1.z) | ((unsigned)f2bf(v1.w) << 16);
  reinterpret_cast<uint4*>(xb)[row * 16 + (g ^ (row & 7))] = o;
  if (gid < (int)(ZERO_BYTES / 16u)) zbase[gid] = make_uint4(0u, 0u, 0u, 0u);
}

// ---- main: fixed 16-col B frags per wave, streamed 32-row LDS panels ----
// Symmetry: per-row hist == per-col hist, so each lane accumulates the hist of
// ONE column (its l16 col) across its 4 acc rows -> packed C01/C23, Cp01/Cp23.
// gS/gSp partials: plain agent-scope (sc1) 8B stores, 16 slots, no atomics.
// Each block LDS-hists its own chunk's 512 labels -> per-strip ccS[bx][128],
// so a strip's finalizer depends only on its 16 handshaked siblings.
// The 16th block of a strip (doneBx; release = __syncthreads vmcnt drain)
// runs the fused epilogue for its 64 cols via agent-scope loads.
__global__ __launch_bounds__(256, 8) void fastap_main_kernel(
    const unsigned short* __restrict__ xb,
    const int* __restrict__ labels,
    float* __restrict__ gS, float* __restrict__ gSp,
    unsigned* __restrict__ gA, unsigned* __restrict__ gAp,
    unsigned* __restrict__ ccS, unsigned* __restrict__ doneBx,
    float* __restrict__ accum, unsigned* __restrict__ done,
    float* __restrict__ out) {
  __shared__ __align__(16) unsigned short sA[2][32 * 128];  // 2 x 8KB row panels
  __shared__ int sLab[ROWCHUNK];                            // this chunk's row labels
  __shared__ int sHist[128];                                // this chunk's class hist
  __shared__ int sFinal;

  const int tid  = threadIdx.x;
  const int wave = tid >> 6;
  const int lane = tid & 63;
  const int l16  = lane & 15;
  const int quad = lane >> 4;
  const int colBase  = blockIdx.x * 64;       // 128 col strips
  const int rowChunk = blockIdx.y * ROWCHUNK; // 16 row chunks

  if (tid < 128) sHist[tid] = 0;
  if (tid < ROWCHUNK / 4)
    reinterpret_cast<int4*>(sLab)[tid] =
        reinterpret_cast<const int4*>(labels + rowChunk)[tid];

  // fixed B fragments: this wave's 16 cols, K=128 (jcol&7 == l16&7)
  const int jcol = colBase + wave * 16 + l16;
  bf16x8 bfr[4];
  #pragma unroll
  for (int kb = 0; kb < 4; ++kb) {
    const int pg = (kb * 4 + quad) ^ (l16 & 7);
    bfr[kb] = *reinterpret_cast<const bf16x8*>(&xb[jcol * 128 + pg * 8]);
  }
  const int labj = labels[jcol];

  f32x2 C01 = {0.f, 0.f}, C23 = {0.f, 0.f};
  f32x2 Cp01 = {0.f, 0.f}, Cp23 = {0.f, 0.f};

  // A-frag ds_read offsets within a 16-row sub-panel (row&7 == l16&7)
  int aOff[4];
  #pragma unroll
  for (int kb = 0; kb < 4; ++kb)
    aOff[kb] = l16 * 128 + (((kb * 4 + quad) ^ (l16 & 7)) << 3);

  // stage panel p's 32 rows (8KB) into buffer b: 2 x 16B per thread
  const unsigned short* xrb = xb + rowChunk * 128;
  auto stage = [&](int p, int b) {
    const unsigned short* src = xrb + p * (32 * 128);
    __builtin_amdgcn_global_load_lds((ag_u32*)(src + tid * 8),
                                     (al_u32*)(&sA[b][tid * 8]), 16, 0, 0);
    __builtin_amdgcn_global_load_lds((ag_u32*)(src + (tid + 256) * 8),
                                     (al_u32*)(&sA[b][(tid + 256) * 8]), 16, 0, 0);
  };

  // one 16-row x 16-col tile; lcr = row offset within chunk (mult of 16)
  auto tile16 = [&](const unsigned short* ap, int lcr) {
    const int4 lr = *reinterpret_cast<const int4*>(&sLab[lcr + quad * 4]);
    bf16x8 a0 = *reinterpret_cast<const bf16x8*>(&ap[aOff[0]]);
    bf16x8 a1 = *reinterpret_cast<const bf16x8*>(&ap[aOff[1]]);
    bf16x8 a2 = *reinterpret_cast<const bf16x8*>(&ap[aOff[2]]);
    bf16x8 a3 = *reinterpret_cast<const bf16x8*>(&ap[aOff[3]]);
    f32x4 acc = {0.f, 0.f, 0.f, 0.f};    // single chain: 8 waves/SIMD hide latency
    acc = __builtin_amdgcn_mfma_f32_16x16x32_bf16(a0, bfr[0], acc, 0, 0, 0);
    acc = __builtin_amdgcn_mfma_f32_16x16x32_bf16(a1, bfr[1], acc, 0, 0, 0);
    acc = __builtin_amdgcn_mfma_f32_16x16x32_bf16(a2, bfr[2], acc, 0, 0, 0);
    acc = __builtin_amdgcn_mfma_f32_16x16x32_bf16(a3, bfr[3], acc, 0, 0, 0);

    const int labr[4] = {lr.x, lr.y, lr.z, lr.w};
    // fast path: pk_fma ramps + med3 clamps. Register bins 3..6 are EXACT
    // for all t: H[k] = clamp01(5a + (k-4)).
    #pragma unroll
    for (int r = 0; r < 4; ++r) {              // D: row = quad*4+r, col = l16
      const float a = acc[r];                  // cos(i, jcol)
      const float pm = (labr[r] == labj) ? 1.f : 0.f;  // diag fixed in rare path
      const f32x2 av = {a, a}, p2 = {pm, pm};
      f32x2 d01 = __builtin_elementwise_fma(av, (f32x2){5.f, 5.f},
                                            (f32x2){-1.f, 0.f});
      f32x2 d23 = __builtin_elementwise_fma(av, (f32x2){5.f, 5.f},
                                            (f32x2){1.f, 2.f});
      d01 = (f32x2){clamp01(d01.x), clamp01(d01.y)};
      d23 = (f32x2){clamp01(d23.x), clamp01(d23.y)};
      C01 += d01; C23 += d23;
      Cp01 = __builtin_elementwise_fma(p2, d01, Cp01);
      Cp23 = __builtin_elementwise_fma(p2, d23, Cp23);
    }

    // one rare check per 4 pairs (abs modifiers are free on v_max)
    const float mabs = fmaxf(fmaxf(fabsf(acc[0]), fabsf(acc[1])),
                             fmaxf(fabsf(acc[2]), fabsf(acc[3])));
    if (__builtin_expect(mabs > 0.4f, 0)) {
      #pragma unroll
      for (int r = 0; r < 4; ++r) {
        const float a = acc[r];
        if (fabsf(a) <= 0.4f) continue;
        const int i = rowChunk + lcr + quad * 4 + r;
        // recompute (bit-identical to fast path)
        const float d0 = clamp01(fmaf(a, 5.f, -1.f));
        const float d1 = clamp01(a * 5.f);
        const float d2 = clamp01(fmaf(a, 5.f, 1.f));
        const float d3 = clamp01(fmaf(a, 5.f, 2.f));
        if (i == jcol) {
          // diagonal: cancel fast contributions (pm was 1) + bins>=7 base (+1)
          C01 -= (f32x2){d0, d1};  C23 -= (f32x2){d2, d3};
          Cp01 -= (f32x2){d0, d1}; Cp23 -= (f32x2){d2, d3};
          #pragma unroll
          for (int k = 7; k <= 10; ++k)
            atomicAdd(&gA[jcol * AROW + k], (unsigned)(-65536));
        } else {
          const bool isPos = (labr[r] == labj);
          const float t = fmaf(a, -5.f, 5.f);
          #pragma unroll
          for (int k = 0; k <= 2; ++k) {       // assumed cumulative 0
            const float v = clamp01((float)(k + 1) - t);
            const int q = (int)(v * 65536.f + 0.5f);
            if (q) {
              atomicAdd(&gA[jcol * AROW + k], (unsigned)q);
              if (isPos) atomicAdd(&gAp[jcol * AROW + k], (unsigned)q);
            }
          }
          #pragma unroll
          for (int k = 7; k <= 10; ++k) {      // assumed cumulative 1
            const float v = clamp01((float)(k + 1) - t) - 1.f;
            const int q = (int)(v * 65536.f - 0.5f);
            if (q) {
              atomicAdd(&gA[jcol * AROW + k], (unsigned)q);
              if (isPos) atomicAdd(&gAp[jcol * AROW + k], (unsigned)q);
            }
          }
        }
      }
    }
  };

  stage(0, 0);
  __syncthreads();             // sLab + sHist-zero visible + panel 0 drained

  // per-block class hist of this chunk's 512 labels (LDS atomics, ~free)
  atomicAdd(&sHist[sLab[tid]], 1);
  atomicAdd(&sHist[sLab[tid + 256]], 1);

  #pragma unroll 1
  for (int p = 0; p < NPANEL; ++p) {
    const int cur = p & 1;
    if (p + 1 < NPANEL) stage(p + 1, cur ^ 1);   // async DMA behind this panel
    tile16(&sA[cur][0],        p * 32);
    tile16(&sA[cur][16 * 128], p * 32 + 16);
    __syncthreads();
  }

  // strip-local class counts: 16 chunk-hists sum to the full 8192-row hist
  if (tid < 128 && sHist[tid])
    atomicAdd(&ccS[blockIdx.x * 128 + tid], (unsigned)sHist[tid]);

  // reduce across the 4 quads sharing each column (lane ^16, ^32)
  #pragma unroll
  for (int m = 16; m < 64; m <<= 1) {
    C01.x  += __shfl_xor(C01.x,  m, 64); C01.y  += __shfl_xor(C01.y,  m, 64);
    C23.x  += __shfl_xor(C23.x,  m, 64); C23.y  += __shfl_xor(C23.y,  m, 64);
    Cp01.x += __shfl_xor(Cp01.x, m, 64); Cp01.y += __shfl_xor(Cp01.y, m, 64);
    Cp23.x += __shfl_xor(Cp23.x, m, 64); Cp23.y += __shfl_xor(Cp23.y, m, 64);
  }

  if (quad == 0) {                // agent-scope 8B stores: coherent, no RMW
    float* b1 = gS  + (unsigned)(blockIdx.y * NS + jcol) * 4u;
    float* b2 = gSp + (unsigned)(blockIdx.y * NS + jcol) * 4u;
    st8_dev(b1,     C01.x,  C01.y);
    st8_dev(b1 + 2, C23.x,  C23.y);
    st8_dev(b2,     Cp01.x, Cp01.y);
    st8_dev(b2 + 2, Cp23.x, Cp23.y);
  }

  // ---- fused finalize: 16th block of this column strip does the epilogue ----
  // Release: __syncthreads drains every lane's vmcnt -> all this block's
  // sc1 stores + atomics are globally performed before tid0's counter bump.
  __syncthreads();
  if (tid == 0)
    sFinal = (atomicAdd(&doneBx[blockIdx.x], 1u) == 15u);
  __syncthreads();
  if (!sFinal) return;

  if (tid < 64) {                       // one col per lane of wave 0
    const int col = colBase + tid;
    const int np = (int)ld4_dev(&ccS[blockIdx.x * 128 + labels[col]]) - 1;

    float Cs[4]  = {0.f, 0.f, 0.f, 0.f};
    float Cps[4] = {0.f, 0.f, 0.f, 0.f};
    #pragma unroll 4
    for (int s = 0; s < 16; ++s) {      // sum the 16 row-chunk partials
      const float* b1 = gS  + (unsigned)(s * NS + col) * 4u;
      const float* b2 = gSp + (unsigned)(s * NS + col) * 4u;
      const float2 u0 = ld8_dev(b1), u1 = ld8_dev(b1 + 2);
      const float2 v0 = ld8_dev(b2), v1 = ld8_dev(b2 + 2);
      Cs[0]  += u0.x; Cs[1]  += u0.y; Cs[2]  += u1.x; Cs[3]  += u1.y;
      Cps[0] += v0.x; Cps[1] += v0.y; Cps[2] += v1.x; Cps[3] += v1.y;
    }
    unsigned gav[11], gapv[11];
    #pragma unroll
    for (int b = 0; b < 11; ++b) {
      gav[b]  = ld4_dev(&gA[col * AROW + b]);
      gapv[b] = ld4_dev(&gAp[col * AROW + b]);
    }

    float ap = 0.f, val = 0.f, HpPrev = 0.f;
    #pragma unroll
    for (int b = 0; b <= 10; ++b) {
      const float baseH  = (b < 3) ? 0.f : (b < 7) ? Cs[b - 3]  : 8192.f;
      const float basePp = (b < 3) ? 0.f : (b < 7) ? Cps[b - 3] : (float)np;
      const float H  = baseH  + (float)(int)gav[b]  * INV64K;
      const float Hp = basePp + (float)(int)gapv[b] * INV64K;
      const float hp = Hp - HpPrev;
      HpPrev = Hp;
      if (H > 1e-6f) ap += hp * Hp / H;
    }
    if (np > 0) { ap /= (float)np; val = 1.f; } else ap = 0.f;

    #pragma unroll
    for (int m = 1; m < 64; m <<= 1) {  // wave-0 shuffle reduce over 64 cols
      ap  += __shfl_xor(ap,  m, 64);
      val += __shfl_xor(val, m, 64);
    }
    if (tid == 0) {
      atomicAdd(&accum[0], ap);
      atomicAdd(&accum[1], val);
      __builtin_amdgcn_s_waitcnt(0);     // accum adds performed before bump
      __asm__ volatile("" ::: "memory");
      const unsigned prev = atomicAdd(done, 1u);
      if (prev == 127u) {                // last of 128 strip finalizers
        const float a2 = atomicAdd(&accum[0], 0.f);   // RMW reads at LLC
        const float c2 = atomicAdd(&accum[1], 0.f);
        out[0] = 1.f - (c2 > 0.f ? a2 / c2 : 0.f);
      }
    }
  }
}

extern "C" void kernel_launch(void* const* d_in, const int* in_sizes, int n_in,
                              void* d_out, int out_size, void* d_ws, size_t ws_size,
                              hipStream_t stream) {
  const float* x      = (const float*)d_in[0];
  const int*   labels = (const int*)d_in[1];
  float* out = (float*)d_out;

  char* ws = (char*)d_ws;
  unsigned short* xb = (unsigned short*)(ws + OFF_XB);
  float*    gS    = (float*)(ws + OFF_GS);
  float*    gSp   = (float*)(ws + OFF_GSP);
  unsigned* gA    = (unsigned*)(ws + OFF_GA);
  unsigned* gAp   = (unsigned*)(ws + OFF_GAP);
  unsigned* ccS   = (unsigned*)(ws + OFF_CS);
  unsigned* dBx   = (unsigned*)(ws + OFF_DB);
  float*    accum = (float*)(ws + OFF_AC);
  unsigned* done  = (unsigned*)(ws + OFF_AC + 8);

  prep_kernel<<<512, 256, 0, stream>>>(x, xb, (uint4*)(ws + OFF_GA));
  fastap_main_kernel<<<dim3(NS / 64, NS / ROWCHUNK), 256, 0, stream>>>(
      xb, labels, gS, gSp, gA, gAp, ccS, dBx, accum, done, out);
}